// Round 1
// baseline (304.421 us; speedup 1.0000x reference)
//
#include <hip/hip_runtime.h>
#include <hip/hip_bf16.h>
#include <math.h>

// CRF negative log-likelihood, fused single kernel.
// B=16384 words, M=16 positions, D=128 features, L=26 labels.
// Mapping: one wave64 per batch element; lane = 2*k + h owns
//   - W[k][h*64 .. h*64+63] in registers (emissions)
//   - T[h*13+u][j=k] columns in registers (recurrence), j == k index reused.

#define B_TOT 16384
#define M_LEN 16
#define D_DIM 128
#define L_LAB 26
#define WPB 4            // waves per block
#define NBLOCKS 1024     // 1024*4 = 4096 waves, 4 batches per wave (divides exactly)

__global__ __launch_bounds__(256, 1) void crf_kernel(
    const float* __restrict__ X, const int* __restrict__ Y,
    const float* __restrict__ W, const float* __restrict__ T,
    float* __restrict__ out)
{
    const int lane = threadIdx.x & 63;
    const int wave = threadIdx.x >> 6;
    const int k2 = lane >> 1;   // label slot 0..31 (valid < 26)
    const int h  = lane & 1;    // half selector

    __shared__ float Ts[L_LAB * L_LAB];              // 2.7 KB
    __shared__ float Xs[WPB][M_LEN * D_DIM];         // 32 KB
    __shared__ float Es[WPB][M_LEN * L_LAB];         // 6.5 KB

    for (int i = threadIdx.x; i < L_LAB * L_LAB; i += 256) Ts[i] = T[i];

    // W fragment in registers: lane (k2,h) holds W[k2][h*64 + 0..63]
    float4 Wr[16];
    if (k2 < L_LAB) {
        const float4* wp = (const float4*)(W + k2 * D_DIM + h * 64);
        #pragma unroll
        for (int i = 0; i < 16; ++i) Wr[i] = wp[i];
    } else {
        #pragma unroll
        for (int i = 0; i < 16; ++i) Wr[i] = make_float4(0.f, 0.f, 0.f, 0.f);
    }

    // T columns in registers: Tr[u] = T[h*13+u][j] with j = k2 (clamped)
    const int jj = (k2 < L_LAB) ? k2 : 0;
    float Tr[13];
    #pragma unroll
    for (int u = 0; u < 13; ++u) {
        Tr[u] = T[(h * 13 + u) * L_LAB + jj];
    }

    __syncthreads();  // Ts ready

    const int wgid = blockIdx.x * WPB + wave;
    const int wstride = gridDim.x * WPB;
    float local = 0.f;  // accumulates (log_z - node - edge) over this wave's batches

    for (int b = wgid; b < B_TOT; b += wstride) {
        // ---- stage X[b] (8 KB) to per-wave LDS, coalesced float4 ----
        const float4* xg = (const float4*)(X + (size_t)b * (M_LEN * D_DIM));
        float4* xs = (float4*)(&Xs[wave][0]);
        #pragma unroll
        for (int i = 0; i < 8; ++i) xs[lane + 64 * i] = xg[lane + 64 * i];
        __syncthreads();

        // ---- emissions: emit[s][k] = <X[b][s], W[k]> ----
        #pragma unroll 4
        for (int s = 0; s < M_LEN; ++s) {
            const float4* xrow = (const float4*)(&Xs[wave][s * D_DIM + h * 64]);
            float acc = 0.f;
            #pragma unroll
            for (int i = 0; i < 16; ++i) {
                float4 x = xrow[i];   // broadcast read: 2 distinct addrs/wave (free 2-way)
                acc += x.x * Wr[i].x + x.y * Wr[i].y + x.z * Wr[i].z + x.w * Wr[i].w;
            }
            acc += __shfl_xor(acc, 1);   // combine the two d-halves
            if (h == 0 && k2 < L_LAB) Es[wave][s * L_LAB + k2] = acc;
        }
        __syncthreads();

        // ---- node + edge potentials ----
        float ne = 0.f;
        if (lane < M_LEN) {
            int ys = Y[(size_t)b * M_LEN + lane];
            ne = Es[wave][lane * L_LAB + ys];
            if (lane < M_LEN - 1) {
                int yn = Y[(size_t)b * M_LEN + lane + 1];
                ne += Ts[ys * L_LAB + yn];
            }
        }
        #pragma unroll
        for (int off = 32; off >= 1; off >>= 1) ne += __shfl_xor(ne, off);

        // ---- forward recurrence (15 steps) ----
        // both lanes of pair (2j,2j+1) end each step holding alpha[j]
        float alpha = 0.f;
        for (int s = 0; s < M_LEN - 1; ++s) {
            float ae = alpha + Es[wave][s * L_LAB + jj];  // lane 2k (and 2k+1) hold alpha[k]+emit[s][k]
            float tq[13];
            float m = -1e30f;
            #pragma unroll
            for (int u = 0; u < 13; ++u) {
                int kk = h * 13 + u;
                float v = __shfl(ae, 2 * kk) + Tr[u];
                tq[u] = v;
                m = fmaxf(m, v);
            }
            m = fmaxf(m, __shfl_xor(m, 1));    // max over all 26 k
            float ss = 0.f;
            #pragma unroll
            for (int u = 0; u < 13; ++u) ss += __expf(tq[u] - m);
            ss += __shfl_xor(ss, 1);           // sum over all 26 k
            alpha = m + __logf(ss);
        }

        // ---- log partition ----
        float fin = (h == 0 && k2 < L_LAB) ? (alpha + Es[wave][(M_LEN - 1) * L_LAB + k2]) : -1e30f;
        float mz = fin;
        #pragma unroll
        for (int off = 32; off >= 1; off >>= 1) mz = fmaxf(mz, __shfl_xor(mz, off));
        float ez = (h == 0 && k2 < L_LAB) ? __expf(fin - mz) : 0.f;
        #pragma unroll
        for (int off = 32; off >= 1; off >>= 1) ez += __shfl_xor(ez, off);
        float logz = mz + __logf(ez);

        local += logz - ne;
        __syncthreads();  // protect Xs/Es before next iteration overwrites
    }

    if (lane == 0) atomicAdd(out, local);
}

extern "C" void kernel_launch(void* const* d_in, const int* in_sizes, int n_in,
                              void* d_out, int out_size, void* d_ws, size_t ws_size,
                              hipStream_t stream) {
    const float* X = (const float*)d_in[0];
    const int*   Y = (const int*)d_in[1];
    const float* W = (const float*)d_in[2];
    const float* T = (const float*)d_in[3];
    float* out = (float*)d_out;

    hipMemsetAsync(out, 0, sizeof(float), stream);
    crf_kernel<<<NBLOCKS, 256, 0, stream>>>(X, Y, W, T, out);
}